// Round 1
// baseline (1837.054 us; speedup 1.0000x reference)
//
#include <hip/hip_runtime.h>

typedef unsigned short u16;
typedef short bf16x8 __attribute__((ext_vector_type(8)));
typedef float f32x4 __attribute__((ext_vector_type(4)));
typedef unsigned short u16x4 __attribute__((ext_vector_type(4)));
typedef unsigned short u16x8 __attribute__((ext_vector_type(8)));

#define B_ 2
#define T_ 2048
#define C_ 512
#define H_ 8
#define FF_ 2048
#define L_ 6
#define V_ 50257
#define M_ (B_*T_)

__device__ __forceinline__ u16 f2b(float f) {
  union { float f; unsigned u; } v; v.f = f;
  unsigned r = v.u + 0x7FFFu + ((v.u >> 16) & 1u);
  return (u16)(r >> 16);
}

__device__ __forceinline__ void async16(const void* g, void* l) {
  __builtin_amdgcn_global_load_lds((const __attribute__((address_space(1))) unsigned int*)g,
                                   (__attribute__((address_space(3))) unsigned int*)l, 16, 0, 0);
}

// ---------------- fp32 -> bf16 conversion ----------------
__global__ void cvt_bf16_k(const f32x4* __restrict__ src, u16x4* __restrict__ dst, int n4) {
  int i = blockIdx.x * blockDim.x + threadIdx.x;
  int stride = gridDim.x * blockDim.x;
  for (; i < n4; i += stride) {
    f32x4 v = src[i];
    u16x4 o;
    o[0] = f2b(v[0]); o[1] = f2b(v[1]); o[2] = f2b(v[2]); o[3] = f2b(v[3]);
    dst[i] = o;
  }
}

// ---------------- embedding: x = wte[idx] + wpe[pos] ----------------
__global__ void embed_k(const int* __restrict__ idx, const float* __restrict__ wte,
                        const float* __restrict__ wpe, float* __restrict__ x) {
  int t = blockIdx.x * 256 + threadIdx.x;   // f32x4 index over M*C/4
  int row = t >> 7;                          // C/4 = 128 vec4 per row
  int c4 = t & 127;
  int tok = idx[row];
  int pos = row & (T_ - 1);
  f32x4 a = ((const f32x4*)(wte + (long)tok * C_))[c4];
  f32x4 p = ((const f32x4*)(wpe + (long)pos * C_))[c4];
  ((f32x4*)x)[t] = a + p;
}

// ---------------- layernorm (fp32 in) -> bf16 out ----------------
__global__ void ln_k(const float* __restrict__ x, const float* __restrict__ w,
                     const float* __restrict__ b, u16* __restrict__ out) {
  int wv = threadIdx.x >> 6;
  int lane = threadIdx.x & 63;
  int row = blockIdx.x * 4 + wv;
  const f32x4* xr = (const f32x4*)(x + (long)row * C_);
  f32x4 v0 = xr[lane * 2], v1 = xr[lane * 2 + 1];
  float s = 0.f, s2 = 0.f;
#pragma unroll
  for (int j = 0; j < 4; j++) { s += v0[j] + v1[j]; s2 += v0[j]*v0[j] + v1[j]*v1[j]; }
#pragma unroll
  for (int off = 32; off >= 1; off >>= 1) { s += __shfl_xor(s, off); s2 += __shfl_xor(s2, off); }
  float mu = s * (1.f / C_);
  float inv = rsqrtf(s2 * (1.f / C_) - mu * mu + 1e-5f);
  const f32x4* wr = (const f32x4*)w;
  const f32x4* br = (const f32x4*)b;
  f32x4 w0 = wr[lane*2], w1 = wr[lane*2+1], b0 = br[lane*2], b1 = br[lane*2+1];
  u16x8 o;
#pragma unroll
  for (int j = 0; j < 4; j++) {
    o[j]     = f2b((v0[j] - mu) * inv * w0[j] + b0[j]);
    o[j + 4] = f2b((v1[j] - mu) * inv * w1[j] + b1[j]);
  }
  *(u16x8*)(out + (long)row * C_ + lane * 8) = o;
}

// ---------------- GEMM: C[M,N] = A[M,K] * B[N,K]^T  (bf16 in, fp32 acc) ----------------
// EPI: 0 = bf16 store, 1 = fp32 residual add into Cf, 2 = gelu -> bf16, 3 = fp32 store w/ N bound
template<int EPI>
__global__ __launch_bounds__(256) void gemm_bt_k(
    const u16* __restrict__ A, const u16* __restrict__ Bw,
    u16* __restrict__ Cb, float* __restrict__ Cf,
    int N, int K, int ldc)
{
  __shared__ __align__(16) u16 sA[2][128 * 32];
  __shared__ __align__(16) u16 sB[2][128 * 32];
  const int tid = threadIdx.x;
  const int n0 = blockIdx.x * 128;
  const int m0 = blockIdx.y * 128;
  const int w = tid >> 6;
  const int lane = tid & 63;
  const int wm = (w >> 1) * 64;
  const int wn = (w & 1) * 64;
  const int g = lane >> 4;
  const int l15 = lane & 15;

  f32x4 acc[4][4] = {};

  const int nk = K >> 5;
  // staging: chunk c covers row c>>2, k8 (c&3)*8 ; issues c = tid and tid+256
  int arow0 = tid >> 2, ak0 = (tid & 3) * 8;
  int c1 = tid + 256;
  int arow1 = c1 >> 2, ak1 = (c1 & 3) * 8;
  int brow0 = n0 + arow0; if (brow0 > N - 1) brow0 = N - 1;
  int brow1 = n0 + arow1; if (brow1 > N - 1) brow1 = N - 1;
  const u16* gA0 = A + (long)(m0 + arow0) * K + ak0;
  const u16* gA1 = A + (long)(m0 + arow1) * K + ak1;
  const u16* gB0 = Bw + (long)brow0 * K + ak0;
  const u16* gB1 = Bw + (long)brow1 * K + ak1;
  const int lb0 = (w * 64) * 8;          // u16 offset of wave's chunk base, issue 0
  const int lb1 = (256 + w * 64) * 8;    // issue 1

  auto stage = [&](int buf, int kt) {
    int ko = kt << 5;
    async16(gA0 + ko, &sA[buf][lb0]);
    async16(gA1 + ko, &sA[buf][lb1]);
    async16(gB0 + ko, &sB[buf][lb0]);
    async16(gB1 + ko, &sB[buf][lb1]);
  };

  stage(0, 0);
  __syncthreads();
  int cur = 0;
  for (int kt = 0; kt < nk; kt++) {
    if (kt + 1 < nk) stage(cur ^ 1, kt + 1);
    const u16* pa = sA[cur];
    const u16* pb = sB[cur];
    bf16x8 af[4], bfr[4];
#pragma unroll
    for (int mt = 0; mt < 4; mt++)
      af[mt] = *(const bf16x8*)(pa + (wm + mt * 16 + l15) * 32 + g * 8);
#pragma unroll
    for (int nt = 0; nt < 4; nt++)
      bfr[nt] = *(const bf16x8*)(pb + (wn + nt * 16 + l15) * 32 + g * 8);
#pragma unroll
    for (int mt = 0; mt < 4; mt++)
#pragma unroll
      for (int nt = 0; nt < 4; nt++)
        acc[mt][nt] = __builtin_amdgcn_mfma_f32_16x16x32_bf16(af[mt], bfr[nt], acc[mt][nt], 0, 0, 0);
    __syncthreads();
    cur ^= 1;
  }

#pragma unroll
  for (int mt = 0; mt < 4; mt++) {
    int m = m0 + wm + mt * 16 + g * 4;
#pragma unroll
    for (int nt = 0; nt < 4; nt++) {
      int n = n0 + wn + nt * 16 + l15;
      f32x4 v = acc[mt][nt];
#pragma unroll
      for (int r = 0; r < 4; r++) {
        long ci = (long)(m + r) * ldc + n;
        if (EPI == 0) {
          Cb[ci] = f2b(v[r]);
        } else if (EPI == 1) {
          Cf[ci] += v[r];
        } else if (EPI == 2) {
          float f = v[r];
          f = 0.5f * f * (1.0f + erff(f * 0.70710678118654752f));
          Cb[ci] = f2b(f);
        } else {
          if (n < N) Cf[ci] = v[r];
        }
      }
    }
  }
}

// ---------------- flash attention (causal), bf16 MFMA, fp32 softmax ----------------
// grid (16, B*H), 256 threads. Block handles q-blocks bx and 31-bx (work-balanced).
__global__ __launch_bounds__(256) void attn_k(const u16* __restrict__ qkv, u16* __restrict__ out) {
  const int bh = blockIdx.y;
  const int b = bh >> 3;
  const int h = bh & 7;
  const int tid = threadIdx.x;
  const int wv = tid >> 6;
  const int lane = tid & 63;
  const int g = lane >> 4;
  const int l15 = lane & 15;
  const int jr = tid >> 3;
  const int c8 = tid & 7;

  __shared__ __align__(16) u16 Ks[32 * 64];
  __shared__ __align__(16) u16 Vt[64 * 32];
  __shared__ __align__(16) u16 Ps[4][16 * 32];

  const long base = (long)b * T_ * 1536;

  for (int half = 0; half < 2; half++) {
    const int qblk = (half == 0) ? blockIdx.x : 31 - blockIdx.x;
    const int q0 = qblk * 64 + wv * 16;

    const u16* qrow = qkv + base + (long)(q0 + l15) * 1536 + h * 64;
    bf16x8 qf0 = *(const bf16x8*)(qrow + g * 8);
    bf16x8 qf1 = *(const bf16x8*)(qrow + 32 + g * 8);

    f32x4 o[4] = {};
    float mrun[4] = {-1e30f, -1e30f, -1e30f, -1e30f};
    float lrun[4] = {0.f, 0.f, 0.f, 0.f};

    const int kv_end = qblk * 64 + 64;
    for (int j0 = 0; j0 < kv_end; j0 += 32) {
      // stage K tile (32x64) and V^T tile (64x32), XOR-swizzled
      {
        const u16* ksrc = qkv + base + (long)(j0 + jr) * 1536 + 512 + h * 64 + c8 * 8;
        u16x8 kv8 = *(const u16x8*)ksrc;
        int chunk = c8 ^ (jr & 7);
        *(u16x8*)(Ks + jr * 64 + chunk * 8) = kv8;
        const u16* vsrc = qkv + base + (long)(j0 + jr) * 1536 + 1024 + h * 64 + c8 * 8;
        u16x8 vv = *(const u16x8*)vsrc;
#pragma unroll
        for (int e = 0; e < 8; e++) {
          int d = c8 * 8 + e;
          int byt = (d * 64 + jr * 2) ^ ((d & 7) << 4);
          Vt[byt >> 1] = vv[e];
        }
      }
      __syncthreads();

      // S = Q K^T (two 16-col tiles)
      f32x4 s0 = {0.f, 0.f, 0.f, 0.f}, s1 = {0.f, 0.f, 0.f, 0.f};
      {
        int row = l15;
        bf16x8 k0 = *(const bf16x8*)(Ks + row * 64 + ((0 * 4 + g) ^ (row & 7)) * 8);
        bf16x8 k1 = *(const bf16x8*)(Ks + row * 64 + ((1 * 4 + g) ^ (row & 7)) * 8);
        s0 = __builtin_amdgcn_mfma_f32_16x16x32_bf16(qf0, k0, s0, 0, 0, 0);
        s0 = __builtin_amdgcn_mfma_f32_16x16x32_bf16(qf1, k1, s0, 0, 0, 0);
        row = 16 + l15;
        k0 = *(const bf16x8*)(Ks + row * 64 + ((0 * 4 + g) ^ (row & 7)) * 8);
        k1 = *(const bf16x8*)(Ks + row * 64 + ((1 * 4 + g) ^ (row & 7)) * 8);
        s1 = __builtin_amdgcn_mfma_f32_16x16x32_bf16(qf0, k0, s1, 0, 0, 0);
        s1 = __builtin_amdgcn_mfma_f32_16x16x32_bf16(qf1, k1, s1, 0, 0, 0);
      }

      // online softmax update + write P (bf16) to swizzled LDS
#pragma unroll
      for (int r = 0; r < 4; r++) {
        int row = q0 + g * 4 + r;
        float v0 = s0[r] * 0.125f;
        float v1 = s1[r] * 0.125f;
        if (j0 + l15 > row) v0 = -1e30f;
        if (j0 + 16 + l15 > row) v1 = -1e30f;
        float mx = fmaxf(v0, v1);
        mx = fmaxf(mx, __shfl_xor(mx, 1));
        mx = fmaxf(mx, __shfl_xor(mx, 2));
        mx = fmaxf(mx, __shfl_xor(mx, 4));
        mx = fmaxf(mx, __shfl_xor(mx, 8));
        float mn = fmaxf(mrun[r], mx);
        float sc = __expf(mrun[r] - mn);
        float e0 = __expf(v0 - mn);
        float e1 = __expf(v1 - mn);
        mrun[r] = mn;
        float rs = e0 + e1;
        rs += __shfl_xor(rs, 1);
        rs += __shfl_xor(rs, 2);
        rs += __shfl_xor(rs, 4);
        rs += __shfl_xor(rs, 8);
        lrun[r] = lrun[r] * sc + rs;
#pragma unroll
        for (int dt = 0; dt < 4; dt++) o[dt][r] *= sc;
        int prow = g * 4 + r;
        int sw = (prow & 7) << 4;
        u16* pw = Ps[wv];
        pw[((prow * 64 + l15 * 2) ^ sw) >> 1] = f2b(e0);
        pw[((prow * 64 + 32 + l15 * 2) ^ sw) >> 1] = f2b(e1);
      }

      // O += P V  (A = P from LDS, B = V^T rows from LDS)
      bf16x8 pf = *(const bf16x8*)(Ps[wv] + (((l15 * 64 + g * 16) ^ ((l15 & 7) << 4)) >> 1));
#pragma unroll
      for (int dt = 0; dt < 4; dt++) {
        int d = dt * 16 + l15;
        bf16x8 vf = *(const bf16x8*)(Vt + (((d * 64 + g * 16) ^ ((d & 7) << 4)) >> 1));
        o[dt] = __builtin_amdgcn_mfma_f32_16x16x32_bf16(pf, vf, o[dt], 0, 0, 0);
      }
      __syncthreads();
    }

#pragma unroll
    for (int r = 0; r < 4; r++) {
      float inv = 1.0f / lrun[r];
      int row = q0 + g * 4 + r;
      u16* orow = out + ((long)(b * T_ + row)) * C_ + h * 64;
#pragma unroll
      for (int dt = 0; dt < 4; dt++)
        orow[dt * 16 + l15] = f2b(o[dt][r] * inv);
    }
  }
}

// ---------------- host launcher ----------------
extern "C" void kernel_launch(void* const* d_in, const int* in_sizes, int n_in,
                              void* d_out, int out_size, void* d_ws, size_t ws_size,
                              hipStream_t stream) {
  const int*   idx    = (const int*)  d_in[0];
  const float* wte    = (const float*)d_in[1];
  const float* wpe    = (const float*)d_in[2];
  const float* ln1w   = (const float*)d_in[3];
  const float* ln1b   = (const float*)d_in[4];
  const float* wattn  = (const float*)d_in[5];
  const float* wcproj = (const float*)d_in[6];
  const float* ln2w   = (const float*)d_in[7];
  const float* ln2b   = (const float*)d_in[8];
  const float* wfc    = (const float*)d_in[9];
  const float* wproj2 = (const float*)d_in[10];
  const float* lnfw   = (const float*)d_in[11];
  const float* lnfb   = (const float*)d_in[12];
  float* out = (float*)d_out;

  char* p = (char*)d_ws;
  size_t off = 0;
  auto alloc = [&](size_t bytes) -> void* {
    void* r = p + off; off += (bytes + 255) & ~(size_t)255; return r;
  };
  float* x    = (float*)alloc((size_t)M_ * C_ * 4);
  u16* xn     = (u16*)alloc((size_t)M_ * C_ * 2);
  u16* qkvb   = (u16*)alloc((size_t)M_ * 3 * C_ * 2);
  u16* attb   = (u16*)alloc((size_t)M_ * C_ * 2);
  u16* hb     = (u16*)alloc((size_t)M_ * FF_ * 2);
  u16* wteB   = (u16*)alloc((size_t)V_ * C_ * 2);
  u16* wattnB = (u16*)alloc((size_t)L_ * 3 * C_ * C_ * 2);
  u16* wprojB = (u16*)alloc((size_t)L_ * C_ * C_ * 2);
  u16* wfcB   = (u16*)alloc((size_t)L_ * FF_ * C_ * 2);
  u16* wp2B   = (u16*)alloc((size_t)L_ * C_ * FF_ * 2);
  if (off > ws_size) return;  // workspace too small: fail visibly

  auto cvt = [&](const float* s, u16* d, long n) {
    int n4 = (int)(n >> 2);
    int blocks = (n4 + 255) / 256; if (blocks > 4096) blocks = 4096;
    cvt_bf16_k<<<dim3(blocks), dim3(256), 0, stream>>>((const f32x4*)s, (u16x4*)d, n4);
  };
  cvt(wte, wteB, (long)V_ * C_);
  cvt(wattn, wattnB, (long)L_ * 3 * C_ * C_);
  cvt(wcproj, wprojB, (long)L_ * C_ * C_);
  cvt(wfc, wfcB, (long)L_ * FF_ * C_);
  cvt(wproj2, wp2B, (long)L_ * C_ * FF_);

  embed_k<<<dim3(M_ * C_ / 4 / 256), dim3(256), 0, stream>>>(idx, wte, wpe, x);

  for (int l = 0; l < L_; l++) {
    ln_k<<<dim3(M_ / 4), dim3(256), 0, stream>>>(x, ln1w + l * C_, ln1b + l * C_, xn);
    gemm_bt_k<0><<<dim3(12, 32), dim3(256), 0, stream>>>(
        xn, wattnB + (size_t)l * 3 * C_ * C_, qkvb, nullptr, 3 * C_, C_, 3 * C_);
    attn_k<<<dim3(16, B_ * H_), dim3(256), 0, stream>>>(qkvb, attb);
    gemm_bt_k<1><<<dim3(4, 32), dim3(256), 0, stream>>>(
        attb, wprojB + (size_t)l * C_ * C_, nullptr, x, C_, C_, C_);
    ln_k<<<dim3(M_ / 4), dim3(256), 0, stream>>>(x, ln2w + l * C_, ln2b + l * C_, xn);
    gemm_bt_k<2><<<dim3(16, 32), dim3(256), 0, stream>>>(
        xn, wfcB + (size_t)l * FF_ * C_, hb, nullptr, FF_, C_, FF_);
    gemm_bt_k<1><<<dim3(4, 32), dim3(256), 0, stream>>>(
        hb, wp2B + (size_t)l * C_ * FF_, nullptr, x, C_, FF_, C_);
  }
  ln_k<<<dim3(M_ / 4), dim3(256), 0, stream>>>(x, lnfw, lnfb, xn);
  gemm_bt_k<3><<<dim3((V_ + 127) / 128, 32), dim3(256), 0, stream>>>(
      xn, wteB, nullptr, out, V_, C_, V_);
}

// Round 2
// 1504.768 us; speedup vs baseline: 1.2208x; 1.2208x over previous
//
#include <hip/hip_runtime.h>

typedef unsigned short u16;
typedef short bf16x8 __attribute__((ext_vector_type(8)));
typedef float f32x4 __attribute__((ext_vector_type(4)));
typedef unsigned short u16x4 __attribute__((ext_vector_type(4)));
typedef unsigned short u16x8 __attribute__((ext_vector_type(8)));
typedef unsigned int u32x2 __attribute__((ext_vector_type(2)));

#define B_ 2
#define T_ 2048
#define C_ 512
#define H_ 8
#define FF_ 2048
#define L_ 6
#define V_ 50257
#define M_ (B_*T_)

__device__ __forceinline__ u16 f2b(float f) {
  union { float f; unsigned u; } v; v.f = f;
  unsigned r = v.u + 0x7FFFu + ((v.u >> 16) & 1u);
  return (u16)(r >> 16);
}
__device__ __forceinline__ float b2f(u16 u) {
  union { unsigned u; float f; } v; v.u = ((unsigned)u) << 16; return v.f;
}
__device__ __forceinline__ unsigned pk_bf16(float lo, float hi) {
  unsigned r;
  asm volatile("v_cvt_pk_bf16_f32 %0, %1, %2" : "=v"(r) : "v"(lo), "v"(hi));
  return r;
}

__device__ __forceinline__ void async16(const void* g, void* l) {
  __builtin_amdgcn_global_load_lds((const __attribute__((address_space(1))) unsigned int*)g,
                                   (__attribute__((address_space(3))) unsigned int*)l, 16, 0, 0);
}

// scale 8 bf16 (as u16x8) by s, return bf16x8
__device__ __forceinline__ bf16x8 scale8(u16x8 v, float s) {
  union { bf16x8 b; unsigned u[4]; } r;
#pragma unroll
  for (int i = 0; i < 4; i++)
    r.u[i] = pk_bf16(b2f(v[2*i]) * s, b2f(v[2*i+1]) * s);
  return r.b;
}

// ---------------- fp32 -> bf16 conversion ----------------
__global__ void cvt_bf16_k(const f32x4* __restrict__ src, u16x4* __restrict__ dst, int n4) {
  int i = blockIdx.x * blockDim.x + threadIdx.x;
  int stride = gridDim.x * blockDim.x;
  for (; i < n4; i += stride) {
    f32x4 v = src[i];
    u16x4 o;
    o[0] = f2b(v[0]); o[1] = f2b(v[1]); o[2] = f2b(v[2]); o[3] = f2b(v[3]);
    dst[i] = o;
  }
}

// ---------------- embedding ----------------
__global__ void embed_k(const int* __restrict__ idx, const float* __restrict__ wte,
                        const float* __restrict__ wpe, float* __restrict__ x) {
  int t = blockIdx.x * 256 + threadIdx.x;
  int row = t >> 7;
  int c4 = t & 127;
  int tok = idx[row];
  int pos = row & (T_ - 1);
  f32x4 a = ((const f32x4*)(wte + (long)tok * C_))[c4];
  f32x4 p = ((const f32x4*)(wpe + (long)pos * C_))[c4];
  ((f32x4*)x)[t] = a + p;
}

// ---------------- layernorm ----------------
__global__ void ln_k(const float* __restrict__ x, const float* __restrict__ w,
                     const float* __restrict__ b, u16* __restrict__ out) {
  int wv = threadIdx.x >> 6;
  int lane = threadIdx.x & 63;
  int row = blockIdx.x * 4 + wv;
  const f32x4* xr = (const f32x4*)(x + (long)row * C_);
  f32x4 v0 = xr[lane * 2], v1 = xr[lane * 2 + 1];
  float s = 0.f, s2 = 0.f;
#pragma unroll
  for (int j = 0; j < 4; j++) { s += v0[j] + v1[j]; s2 += v0[j]*v0[j] + v1[j]*v1[j]; }
#pragma unroll
  for (int off = 32; off >= 1; off >>= 1) { s += __shfl_xor(s, off); s2 += __shfl_xor(s2, off); }
  float mu = s * (1.f / C_);
  float inv = rsqrtf(s2 * (1.f / C_) - mu * mu + 1e-5f);
  const f32x4* wr = (const f32x4*)w;
  const f32x4* br = (const f32x4*)b;
  f32x4 w0 = wr[lane*2], w1 = wr[lane*2+1], b0 = br[lane*2], b1 = br[lane*2+1];
  u16x8 o;
#pragma unroll
  for (int j = 0; j < 4; j++) {
    o[j]     = f2b((v0[j] - mu) * inv * w0[j] + b0[j]);
    o[j + 4] = f2b((v1[j] - mu) * inv * w1[j] + b1[j]);
  }
  *(u16x8*)(out + (long)row * C_ + lane * 8) = o;
}

// ---------------- GEMM: C[M,N] = A[M,K] * B[N,K]^T ----------------
// EPI: 0 = bf16 store, 1 = fp32 residual add, 2 = gelu->bf16, 3 = fp32 store w/ N bound
// BM: 128 or 64 (BN fixed at 128)
template<int EPI, int BM>
__global__ __launch_bounds__(256) void gemm_bt_k(
    const u16* __restrict__ A, const u16* __restrict__ Bw,
    u16* __restrict__ Cb, float* __restrict__ Cf,
    int N, int K, int ldc)
{
  constexpr int MT = BM / 32;   // m-tiles of 16 per wave
  __shared__ __align__(16) u16 sA[2][BM * 32];
  __shared__ __align__(16) u16 sB[2][128 * 32];
  const int tid = threadIdx.x;
  const int n0 = blockIdx.x * 128;
  const int m0 = blockIdx.y * BM;
  const int w = tid >> 6;
  const int lane = tid & 63;
  const int wm = (w >> 1) * (BM / 2);
  const int wn = (w & 1) * 64;
  const int g = lane >> 4;
  const int l15 = lane & 15;

  f32x4 acc[MT][4] = {};

  const int nk = K >> 5;
  int arow0 = tid >> 2, ak0 = (tid & 3) * 8;
  int c1 = tid + 256;
  int arow1 = c1 >> 2, ak1 = (c1 & 3) * 8;
  int brow0 = n0 + arow0; if (brow0 > N - 1) brow0 = N - 1;
  int brow1 = n0 + arow1; if (brow1 > N - 1) brow1 = N - 1;
  const u16* gA0 = A + (long)(m0 + arow0) * K + ak0;
  const u16* gA1 = A + (long)(m0 + arow1) * K + ak1;   // only used when BM==128
  const u16* gB0 = Bw + (long)brow0 * K + ak0;
  const u16* gB1 = Bw + (long)brow1 * K + ak1;
  const int lb0 = (w * 64) * 8;
  const int lb1 = (256 + w * 64) * 8;

  auto stage = [&](int buf, int kt) {
    int ko = kt << 5;
    async16(gA0 + ko, &sA[buf][lb0]);
    if constexpr (BM == 128) async16(gA1 + ko, &sA[buf][lb1]);
    async16(gB0 + ko, &sB[buf][lb0]);
    async16(gB1 + ko, &sB[buf][lb1]);
  };

  stage(0, 0);
  __syncthreads();
  int cur = 0;
  for (int kt = 0; kt < nk; kt++) {
    if (kt + 1 < nk) stage(cur ^ 1, kt + 1);
    const u16* pa = sA[cur];
    const u16* pb = sB[cur];
    bf16x8 af[MT], bfr[4];
#pragma unroll
    for (int mt = 0; mt < MT; mt++)
      af[mt] = *(const bf16x8*)(pa + (wm + mt * 16 + l15) * 32 + g * 8);
#pragma unroll
    for (int nt = 0; nt < 4; nt++)
      bfr[nt] = *(const bf16x8*)(pb + (wn + nt * 16 + l15) * 32 + g * 8);
#pragma unroll
    for (int mt = 0; mt < MT; mt++)
#pragma unroll
      for (int nt = 0; nt < 4; nt++)
        acc[mt][nt] = __builtin_amdgcn_mfma_f32_16x16x32_bf16(af[mt], bfr[nt], acc[mt][nt], 0, 0, 0);
    __syncthreads();
    cur ^= 1;
  }

#pragma unroll
  for (int mt = 0; mt < MT; mt++) {
    int m = m0 + wm + mt * 16 + g * 4;
#pragma unroll
    for (int nt = 0; nt < 4; nt++) {
      int n = n0 + wn + nt * 16 + l15;
      f32x4 v = acc[mt][nt];
#pragma unroll
      for (int r = 0; r < 4; r++) {
        long ci = (long)(m + r) * ldc + n;
        if (EPI == 0) {
          Cb[ci] = f2b(v[r]);
        } else if (EPI == 1) {
          Cf[ci] += v[r];
        } else if (EPI == 2) {
          float f = v[r];
          f = 0.5f * f * (1.0f + erff(f * 0.70710678118654752f));
          Cb[ci] = f2b(f);
        } else {
          if (n < N) Cf[ci] = v[r];
        }
      }
    }
  }
}

// ---------------- flash attention v2 ----------------
// grid (32, B*H), 128 threads (2 waves). Block bx handles 32 q-rows of qblk
// (bx>>1) in phase 0 and of qblk 31-(bx>>1) in phase 1 -> uniform 33 KV-steps.
// KVBLK=64, double-buffered K (async16, pre-swizzled source) and V^T
// (reg-staged, k-quad-packed b64 writes, pad-72 rows). Softmax: exp2 domain
// (scale folded into Q), defer-max THR=8, lane-local partial row sums.
// P stored in kv-PERMUTED order k' = l15*4 + t (matching permuted V^T) so the
// P write is cvt_pk + one ds_write_b64 per row, no shfl/f2b.
__global__ __launch_bounds__(128) void attn_k(const u16* __restrict__ qkv, u16* __restrict__ out) {
  const int bh = blockIdx.y;
  const int b = bh >> 3;
  const int h = bh & 7;
  const int tid = threadIdx.x;
  const int wv = tid >> 6;
  const int lane = tid & 63;
  const int g = lane >> 4;
  const int l15 = lane & 15;
  const int qA = blockIdx.x >> 1;
  const int halfsel = blockIdx.x & 1;

  __shared__ __align__(16) u16 Ks[2][64 * 64];
  __shared__ __align__(16) u16 Vt[2][64 * 72];   // [d][k'] pad-72
  __shared__ __align__(16) u16 Ps[2][16 * 64];   // per-wave, [q][k'] XOR-swizzled

  const long base = (long)b * T_ * 1536;
  const u16* kbase = qkv + base + 512 + h * 64;
  const u16* vbase = qkv + base + 1024 + h * 64;
  const int kq = tid & 15;     // V-stage: k' group (actual rows kq+16t)
  const int dg = tid >> 4;     // V-stage: d = dg*8 .. +8
  const float qscale = 0.18033688011112042f;  // 1/sqrt(64) * log2(e)

  for (int ph = 0; ph < 2; ph++) {
    const int qblk = (ph == 0) ? qA : 31 - qA;
    const int q0 = qblk * 64 + halfsel * 32 + wv * 16;

    const u16* qrow = qkv + base + (long)(q0 + l15) * 1536 + h * 64;
    bf16x8 qf0 = scale8(*(const u16x8*)(qrow + g * 8), qscale);
    bf16x8 qf1 = scale8(*(const u16x8*)(qrow + 32 + g * 8), qscale);

    f32x4 o[4] = {};
    float mrun[4] = {-1e30f, -1e30f, -1e30f, -1e30f};
    float lrun[4] = {0.f, 0.f, 0.f, 0.f};
    const int kvend = qblk * 64 + 64;

    u16x8 vreg[4];
    // ---- prologue: stage tile 0 ----
#pragma unroll
    for (int i = 0; i < 4; i++) {
      int chunk = i * 128 + tid;
      int row = chunk >> 3, c8 = chunk & 7;
      async16(kbase + (long)row * 1536 + (c8 ^ (row & 7)) * 8,
              &Ks[0][(i * 128 + wv * 64) * 8]);
    }
#pragma unroll
    for (int t = 0; t < 4; t++)
      vreg[t] = *(const u16x8*)(vbase + (long)(kq + 16 * t) * 1536 + dg * 8);
#pragma unroll
    for (int e = 0; e < 8; e++) {
      int d = dg * 8 + e;
      u32x2 wq = { (unsigned)vreg[0][e] | ((unsigned)vreg[1][e] << 16),
                   (unsigned)vreg[2][e] | ((unsigned)vreg[3][e] << 16) };
      *(u32x2*)(&Vt[0][d * 72 + kq * 4]) = wq;
    }
    __syncthreads();

    int cur = 0;
    for (int j0 = 0; j0 < kvend; j0 += 64, cur ^= 1) {
      const bool more = (j0 + 64) < kvend;
      if (more) {
        int jn = j0 + 64;
#pragma unroll
        for (int i = 0; i < 4; i++) {
          int chunk = i * 128 + tid;
          int row = chunk >> 3, c8 = chunk & 7;
          async16(kbase + (long)(jn + row) * 1536 + (c8 ^ (row & 7)) * 8,
                  &Ks[cur ^ 1][(i * 128 + wv * 64) * 8]);
        }
#pragma unroll
        for (int t = 0; t < 4; t++)
          vreg[t] = *(const u16x8*)(vbase + (long)(jn + kq + 16 * t) * 1536 + dg * 8);
      }

      // ---- QK^T: S[q][kv], 4 kv-tiles ----
      f32x4 s[4] = {};
      const u16* kp = Ks[cur];
#pragma unroll
      for (int t = 0; t < 4; t++) {
        int row = t * 16 + l15;
        const u16* kr = kp + row * 64;
        bf16x8 k0 = *(const bf16x8*)(kr + ((g ^ (row & 7)) * 8));
        bf16x8 k1 = *(const bf16x8*)(kr + (((4 + g) ^ (row & 7)) * 8));
        s[t] = __builtin_amdgcn_mfma_f32_16x16x32_bf16(qf0, k0, s[t], 0, 0, 0);
        s[t] = __builtin_amdgcn_mfma_f32_16x16x32_bf16(qf1, k1, s[t], 0, 0, 0);
      }

      const bool diag = (j0 + 64) == kvend;
      u16* pw = Ps[wv];
#pragma unroll
      for (int r = 0; r < 4; r++) {
        int row = q0 + g * 4 + r;
        float v0 = s[0][r], v1 = s[1][r], v2 = s[2][r], v3 = s[3][r];
        if (diag) {
          if (j0 +      l15 > row) v0 = -1e30f;
          if (j0 + 16 + l15 > row) v1 = -1e30f;
          if (j0 + 32 + l15 > row) v2 = -1e30f;
          if (j0 + 48 + l15 > row) v3 = -1e30f;
        }
        float mloc = fmaxf(fmaxf(v0, v1), fmaxf(v2, v3));
        float m = mrun[r];
        if (!__all(mloc <= m + 8.0f)) {
          float mx = mloc;
          mx = fmaxf(mx, __shfl_xor(mx, 1));
          mx = fmaxf(mx, __shfl_xor(mx, 2));
          mx = fmaxf(mx, __shfl_xor(mx, 4));
          mx = fmaxf(mx, __shfl_xor(mx, 8));
          float mn = fmaxf(m, mx);
          float sc2 = exp2f(m - mn);
          lrun[r] *= sc2;
#pragma unroll
          for (int dt = 0; dt < 4; dt++) o[dt][r] *= sc2;
          m = mn; mrun[r] = mn;
        }
        float e0 = exp2f(v0 - m), e1 = exp2f(v1 - m);
        float e2 = exp2f(v2 - m), e3 = exp2f(v3 - m);
        lrun[r] += (e0 + e1) + (e2 + e3);
        u32x2 pkq = { pk_bf16(e0, e1), pk_bf16(e2, e3) };
        int prow = g * 4 + r;
        int byt = prow * 128 + ((((l15 >> 1) ^ (prow & 7)) << 4)) + (l15 & 1) * 8;
        *(u32x2*)((char*)pw + byt) = pkq;
      }

      // ---- PV: O[q][d] += P'[q][k'] V'[k'][d] (permuted k') ----
      const u16* vt = Vt[cur];
      bf16x8 pf0 = *(const bf16x8*)((char*)pw + l15 * 128 + (((g) ^ (l15 & 7)) << 4));
      bf16x8 pf1 = *(const bf16x8*)((char*)pw + l15 * 128 + (((4 + g) ^ (l15 & 7)) << 4));
#pragma unroll
      for (int dt = 0; dt < 4; dt++) {
        int d = dt * 16 + l15;
        bf16x8 vf0 = *(const bf16x8*)(vt + d * 72 + g * 8);
        bf16x8 vf1 = *(const bf16x8*)(vt + d * 72 + 32 + g * 8);
        o[dt] = __builtin_amdgcn_mfma_f32_16x16x32_bf16(pf0, vf0, o[dt], 0, 0, 0);
        o[dt] = __builtin_amdgcn_mfma_f32_16x16x32_bf16(pf1, vf1, o[dt], 0, 0, 0);
      }

      if (more) {
#pragma unroll
        for (int e = 0; e < 8; e++) {
          int d = dg * 8 + e;
          u32x2 wq = { (unsigned)vreg[0][e] | ((unsigned)vreg[1][e] << 16),
                       (unsigned)vreg[2][e] | ((unsigned)vreg[3][e] << 16) };
          *(u32x2*)(&Vt[cur ^ 1][d * 72 + kq * 4]) = wq;
        }
      }
      __syncthreads();
    }

    // ---- epilogue ----
#pragma unroll
    for (int r = 0; r < 4; r++) {
      float ls = lrun[r];
      ls += __shfl_xor(ls, 1); ls += __shfl_xor(ls, 2);
      ls += __shfl_xor(ls, 4); ls += __shfl_xor(ls, 8);
      float inv = 1.0f / ls;
      int row = q0 + g * 4 + r;
      u16* orow = out + (long)(b * T_ + row) * C_ + h * 64;
#pragma unroll
      for (int dt = 0; dt < 4; dt++)
        orow[dt * 16 + l15] = f2b(o[dt][r] * inv);
    }
  }
}

// ---------------- host launcher ----------------
extern "C" void kernel_launch(void* const* d_in, const int* in_sizes, int n_in,
                              void* d_out, int out_size, void* d_ws, size_t ws_size,
                              hipStream_t stream) {
  const int*   idx    = (const int*)  d_in[0];
  const float* wte    = (const float*)d_in[1];
  const float* wpe    = (const float*)d_in[2];
  const float* ln1w   = (const float*)d_in[3];
  const float* ln1b   = (const float*)d_in[4];
  const float* wattn  = (const float*)d_in[5];
  const float* wcproj = (const float*)d_in[6];
  const float* ln2w   = (const float*)d_in[7];
  const float* ln2b   = (const float*)d_in[8];
  const float* wfc    = (const float*)d_in[9];
  const float* wproj2 = (const float*)d_in[10];
  const float* lnfw   = (const float*)d_in[11];
  const float* lnfb   = (const float*)d_in[12];
  float* out = (float*)d_out;

  char* p = (char*)d_ws;
  size_t off = 0;
  auto alloc = [&](size_t bytes) -> void* {
    void* r = p + off; off += (bytes + 255) & ~(size_t)255; return r;
  };
  float* x    = (float*)alloc((size_t)M_ * C_ * 4);
  u16* xn     = (u16*)alloc((size_t)M_ * C_ * 2);
  u16* qkvb   = (u16*)alloc((size_t)M_ * 3 * C_ * 2);
  u16* attb   = (u16*)alloc((size_t)M_ * C_ * 2);
  u16* hb     = (u16*)alloc((size_t)M_ * FF_ * 2);
  u16* wteB   = (u16*)alloc((size_t)V_ * C_ * 2);
  u16* wattnB = (u16*)alloc((size_t)L_ * 3 * C_ * C_ * 2);
  u16* wprojB = (u16*)alloc((size_t)L_ * C_ * C_ * 2);
  u16* wfcB   = (u16*)alloc((size_t)L_ * FF_ * C_ * 2);
  u16* wp2B   = (u16*)alloc((size_t)L_ * C_ * FF_ * 2);
  if (off > ws_size) return;

  auto cvt = [&](const float* s, u16* d, long n) {
    int n4 = (int)(n >> 2);
    int blocks = (n4 + 255) / 256; if (blocks > 4096) blocks = 4096;
    cvt_bf16_k<<<dim3(blocks), dim3(256), 0, stream>>>((const f32x4*)s, (u16x4*)d, n4);
  };
  cvt(wte, wteB, (long)V_ * C_);
  cvt(wattn, wattnB, (long)L_ * 3 * C_ * C_);
  cvt(wcproj, wprojB, (long)L_ * C_ * C_);
  cvt(wfc, wfcB, (long)L_ * FF_ * C_);
  cvt(wproj2, wp2B, (long)L_ * C_ * FF_);

  embed_k<<<dim3(M_ * C_ / 4 / 256), dim3(256), 0, stream>>>(idx, wte, wpe, x);

  for (int l = 0; l < L_; l++) {
    ln_k<<<dim3(M_ / 4), dim3(256), 0, stream>>>(x, ln1w + l * C_, ln1b + l * C_, xn);
    gemm_bt_k<0, 64><<<dim3(12, 64), dim3(256), 0, stream>>>(
        xn, wattnB + (size_t)l * 3 * C_ * C_, qkvb, nullptr, 3 * C_, C_, 3 * C_);
    attn_k<<<dim3(32, B_ * H_), dim3(128), 0, stream>>>(qkvb, attb);
    gemm_bt_k<1, 64><<<dim3(4, 64), dim3(256), 0, stream>>>(
        attb, wprojB + (size_t)l * C_ * C_, nullptr, x, C_, C_, C_);
    ln_k<<<dim3(M_ / 4), dim3(256), 0, stream>>>(x, ln2w + l * C_, ln2b + l * C_, xn);
    gemm_bt_k<2, 128><<<dim3(16, 32), dim3(256), 0, stream>>>(
        xn, wfcB + (size_t)l * FF_ * C_, hb, nullptr, FF_, C_, FF_);
    gemm_bt_k<1, 64><<<dim3(4, 64), dim3(256), 0, stream>>>(
        hb, wp2B + (size_t)l * C_ * FF_, nullptr, x, C_, FF_, C_);
  }
  ln_k<<<dim3(M_ / 4), dim3(256), 0, stream>>>(x, lnfw, lnfb, xn);
  gemm_bt_k<3, 128><<<dim3((V_ + 127) / 128, 32), dim3(256), 0, stream>>>(
      xn, wteB, nullptr, out, V_, C_, V_);
}

// Round 3
// 1422.087 us; speedup vs baseline: 1.2918x; 1.0581x over previous
//
#include <hip/hip_runtime.h>

typedef unsigned short u16;
typedef short bf16x8 __attribute__((ext_vector_type(8)));
typedef float f32x4 __attribute__((ext_vector_type(4)));
typedef unsigned short u16x4 __attribute__((ext_vector_type(4)));
typedef unsigned short u16x8 __attribute__((ext_vector_type(8)));
typedef unsigned int u32x2 __attribute__((ext_vector_type(2)));

#define B_ 2
#define T_ 2048
#define C_ 512
#define H_ 8
#define FF_ 2048
#define L_ 6
#define V_ 50257
#define M_ (B_*T_)

__device__ __forceinline__ u16 f2b(float f) {
  union { float f; unsigned u; } v; v.f = f;
  unsigned r = v.u + 0x7FFFu + ((v.u >> 16) & 1u);
  return (u16)(r >> 16);
}
__device__ __forceinline__ float b2f(u16 u) {
  union { unsigned u; float f; } v; v.u = ((unsigned)u) << 16; return v.f;
}
__device__ __forceinline__ unsigned pk_bf16(float lo, float hi) {
  unsigned r;
  asm volatile("v_cvt_pk_bf16_f32 %0, %1, %2" : "=v"(r) : "v"(lo), "v"(hi));
  return r;
}

__device__ __forceinline__ void async16(const void* g, void* l) {
  __builtin_amdgcn_global_load_lds((const __attribute__((address_space(1))) unsigned int*)g,
                                   (__attribute__((address_space(3))) unsigned int*)l, 16, 0, 0);
}

__device__ __forceinline__ bf16x8 scale8(u16x8 v, float s) {
  union { bf16x8 b; unsigned u[4]; } r;
#pragma unroll
  for (int i = 0; i < 4; i++)
    r.u[i] = pk_bf16(b2f(v[2*i]) * s, b2f(v[2*i+1]) * s);
  return r.b;
}

// ---------------- fp32 -> bf16 conversion ----------------
__global__ void cvt_bf16_k(const f32x4* __restrict__ src, u16x4* __restrict__ dst, int n4) {
  int i = blockIdx.x * blockDim.x + threadIdx.x;
  int stride = gridDim.x * blockDim.x;
  for (; i < n4; i += stride) {
    f32x4 v = src[i];
    u16x4 o;
    o[0] = f2b(v[0]); o[1] = f2b(v[1]); o[2] = f2b(v[2]); o[3] = f2b(v[3]);
    dst[i] = o;
  }
}

// ---------------- embedding ----------------
__global__ void embed_k(const int* __restrict__ idx, const float* __restrict__ wte,
                        const float* __restrict__ wpe, float* __restrict__ x) {
  int t = blockIdx.x * 256 + threadIdx.x;
  int row = t >> 7;
  int c4 = t & 127;
  int tok = idx[row];
  int pos = row & (T_ - 1);
  f32x4 a = ((const f32x4*)(wte + (long)tok * C_))[c4];
  f32x4 p = ((const f32x4*)(wpe + (long)pos * C_))[c4];
  ((f32x4*)x)[t] = a + p;
}

// ---------------- layernorm ----------------
__global__ void ln_k(const float* __restrict__ x, const float* __restrict__ w,
                     const float* __restrict__ b, u16* __restrict__ out) {
  int wv = threadIdx.x >> 6;
  int lane = threadIdx.x & 63;
  int row = blockIdx.x * 4 + wv;
  const f32x4* xr = (const f32x4*)(x + (long)row * C_);
  f32x4 v0 = xr[lane * 2], v1 = xr[lane * 2 + 1];
  float s = 0.f, s2 = 0.f;
#pragma unroll
  for (int j = 0; j < 4; j++) { s += v0[j] + v1[j]; s2 += v0[j]*v0[j] + v1[j]*v1[j]; }
#pragma unroll
  for (int off = 32; off >= 1; off >>= 1) { s += __shfl_xor(s, off); s2 += __shfl_xor(s2, off); }
  float mu = s * (1.f / C_);
  float inv = rsqrtf(s2 * (1.f / C_) - mu * mu + 1e-5f);
  const f32x4* wr = (const f32x4*)w;
  const f32x4* br = (const f32x4*)b;
  f32x4 w0 = wr[lane*2], w1 = wr[lane*2+1], b0 = br[lane*2], b1 = br[lane*2+1];
  u16x8 o;
#pragma unroll
  for (int j = 0; j < 4; j++) {
    o[j]     = f2b((v0[j] - mu) * inv * w0[j] + b0[j]);
    o[j + 4] = f2b((v1[j] - mu) * inv * w1[j] + b1[j]);
  }
  *(u16x8*)(out + (long)row * C_ + lane * 8) = o;
}

// ---------------- GEMM: C[M,N] = A[M,K] * B[N,K]^T ----------------
// EPI: 0 = bf16 store, 1 = fp32 residual add, 2 = gelu->bf16
template<int EPI, int BM>
__global__ __launch_bounds__(256) void gemm_bt_k(
    const u16* __restrict__ A, const u16* __restrict__ Bw,
    u16* __restrict__ Cb, float* __restrict__ Cf,
    int N, int K, int ldc)
{
  constexpr int MT = BM / 32;
  __shared__ __align__(16) u16 sA[2][BM * 32];
  __shared__ __align__(16) u16 sB[2][128 * 32];
  const int tid = threadIdx.x;
  const int n0 = blockIdx.x * 128;
  const int m0 = blockIdx.y * BM;
  const int w = tid >> 6;
  const int lane = tid & 63;
  const int wm = (w >> 1) * (BM / 2);
  const int wn = (w & 1) * 64;
  const int g = lane >> 4;
  const int l15 = lane & 15;

  f32x4 acc[MT][4] = {};

  const int nk = K >> 5;
  int arow0 = tid >> 2, ak0 = (tid & 3) * 8;
  int c1 = tid + 256;
  int arow1 = c1 >> 2, ak1 = (c1 & 3) * 8;
  int brow0 = n0 + arow0; if (brow0 > N - 1) brow0 = N - 1;
  int brow1 = n0 + arow1; if (brow1 > N - 1) brow1 = N - 1;
  const u16* gA0 = A + (long)(m0 + arow0) * K + ak0;
  const u16* gA1 = A + (long)(m0 + arow1) * K + ak1;
  const u16* gB0 = Bw + (long)brow0 * K + ak0;
  const u16* gB1 = Bw + (long)brow1 * K + ak1;
  const int lb0 = (w * 64) * 8;
  const int lb1 = (256 + w * 64) * 8;

  auto stage = [&](int buf, int kt) {
    int ko = kt << 5;
    async16(gA0 + ko, &sA[buf][lb0]);
    if constexpr (BM == 128) async16(gA1 + ko, &sA[buf][lb1]);
    async16(gB0 + ko, &sB[buf][lb0]);
    async16(gB1 + ko, &sB[buf][lb1]);
  };

  stage(0, 0);
  __syncthreads();
  int cur = 0;
  for (int kt = 0; kt < nk; kt++) {
    if (kt + 1 < nk) stage(cur ^ 1, kt + 1);
    const u16* pa = sA[cur];
    const u16* pb = sB[cur];
    bf16x8 af[MT], bfr[4];
#pragma unroll
    for (int mt = 0; mt < MT; mt++)
      af[mt] = *(const bf16x8*)(pa + (wm + mt * 16 + l15) * 32 + g * 8);
#pragma unroll
    for (int nt = 0; nt < 4; nt++)
      bfr[nt] = *(const bf16x8*)(pb + (wn + nt * 16 + l15) * 32 + g * 8);
#pragma unroll
    for (int mt = 0; mt < MT; mt++)
#pragma unroll
      for (int nt = 0; nt < 4; nt++)
        acc[mt][nt] = __builtin_amdgcn_mfma_f32_16x16x32_bf16(af[mt], bfr[nt], acc[mt][nt], 0, 0, 0);
    __syncthreads();
    cur ^= 1;
  }

#pragma unroll
  for (int mt = 0; mt < MT; mt++) {
    int m = m0 + wm + mt * 16 + g * 4;
#pragma unroll
    for (int nt = 0; nt < 4; nt++) {
      int n = n0 + wn + nt * 16 + l15;
      f32x4 v = acc[mt][nt];
#pragma unroll
      for (int r = 0; r < 4; r++) {
        long ci = (long)(m + r) * ldc + n;
        if (EPI == 0) {
          Cb[ci] = f2b(v[r]);
        } else if (EPI == 1) {
          Cf[ci] += v[r];
        } else {
          float f = v[r];
          f = 0.5f * f * (1.0f + erff(f * 0.70710678118654752f));
          Cb[ci] = f2b(f);
        }
      }
    }
  }
}

// ---------------- lm_head GEMM: BM=256, BN=128, 512 threads (8 waves 4Mx2N) ----------
// K=512 fixed. XCD-swizzled linear grid; out = fp32 with n<N bound.
__global__ __launch_bounds__(512) void gemm_lmhead_k(
    const u16* __restrict__ A, const u16* __restrict__ Bw,
    float* __restrict__ Cf, int N)
{
  __shared__ __align__(16) u16 sA[2][256 * 32];
  __shared__ __align__(16) u16 sB[2][128 * 32];
  const int K = 512;
  const int nwg = gridDim.x;            // 6288 = 8 * 786
  const int cpx = nwg >> 3;
  const int bid = blockIdx.x;
  const int swz = (bid & 7) * cpx + (bid >> 3);
  const int ntiles = (N + 127) >> 7;    // 393
  const int n0 = (swz % ntiles) * 128;
  const int m0 = (swz / ntiles) * 256;
  const int tid = threadIdx.x;
  const int w = tid >> 6;
  const int lane = tid & 63;
  const int wm = (w >> 1) * 64;
  const int wn = (w & 1) * 64;
  const int g = lane >> 4;
  const int l15 = lane & 15;

  f32x4 acc[4][4] = {};

  // A: 1024 16B-chunks (2/thread), B: 512 chunks (1/thread)
  const int ac1 = tid + 512;
  const u16* gA0 = A + (long)(m0 + (tid >> 2)) * K + (tid & 3) * 8;
  const u16* gA1 = A + (long)(m0 + (ac1 >> 2)) * K + (ac1 & 3) * 8;
  int brow = n0 + (tid >> 2); if (brow > N - 1) brow = N - 1;
  const u16* gB0 = Bw + (long)brow * K + (tid & 3) * 8;
  const int lbA0 = (w * 64) * 8;
  const int lbA1 = (512 + w * 64) * 8;
  const int lbB0 = (w * 64) * 8;

  auto stage = [&](int buf, int kt) {
    int ko = kt << 5;
    async16(gA0 + ko, &sA[buf][lbA0]);
    async16(gA1 + ko, &sA[buf][lbA1]);
    async16(gB0 + ko, &sB[buf][lbB0]);
  };

  stage(0, 0);
  __syncthreads();
  int cur = 0;
  const int nk = K >> 5;   // 16
  for (int kt = 0; kt < nk; kt++) {
    if (kt + 1 < nk) stage(cur ^ 1, kt + 1);
    const u16* pa = sA[cur];
    const u16* pb = sB[cur];
    bf16x8 af[4], bfr[4];
#pragma unroll
    for (int mt = 0; mt < 4; mt++)
      af[mt] = *(const bf16x8*)(pa + (wm + mt * 16 + l15) * 32 + g * 8);
#pragma unroll
    for (int nt = 0; nt < 4; nt++)
      bfr[nt] = *(const bf16x8*)(pb + (wn + nt * 16 + l15) * 32 + g * 8);
#pragma unroll
    for (int mt = 0; mt < 4; mt++)
#pragma unroll
      for (int nt = 0; nt < 4; nt++)
        acc[mt][nt] = __builtin_amdgcn_mfma_f32_16x16x32_bf16(af[mt], bfr[nt], acc[mt][nt], 0, 0, 0);
    __syncthreads();
    cur ^= 1;
  }

#pragma unroll
  for (int mt = 0; mt < 4; mt++) {
    int m = m0 + wm + mt * 16 + g * 4;
#pragma unroll
    for (int nt = 0; nt < 4; nt++) {
      int n = n0 + wn + nt * 16 + l15;
      f32x4 v = acc[mt][nt];
      if (n < N) {
#pragma unroll
        for (int r = 0; r < 4; r++)
          Cf[(long)(m + r) * N + n] = v[r];
      }
    }
  }
}

// ---------------- flash attention v3 ----------------
// grid (64, B*H), 128 threads (2 waves). Block bx handles the 32 q-rows of
// qblk = 31-(bx>>1), half (bx&1) -> 1024 blocks, 2048 waves = 2 waves/SIMD.
// Long blocks (qblk 31) dispatch first so the scheduler back-fills the tail.
__global__ __launch_bounds__(128) void attn_k(const u16* __restrict__ qkv, u16* __restrict__ out) {
  const int bh = blockIdx.y;
  const int b = bh >> 3;
  const int h = bh & 7;
  const int tid = threadIdx.x;
  const int wv = tid >> 6;
  const int lane = tid & 63;
  const int g = lane >> 4;
  const int l15 = lane & 15;
  const int qblk = 31 - (blockIdx.x >> 1);
  const int halfsel = blockIdx.x & 1;

  __shared__ __align__(16) u16 Ks[2][64 * 64];
  __shared__ __align__(16) u16 Vt[2][64 * 72];
  __shared__ __align__(16) u16 Ps[2][16 * 64];

  const long base = (long)b * T_ * 1536;
  const u16* kbase = qkv + base + 512 + h * 64;
  const u16* vbase = qkv + base + 1024 + h * 64;
  const int kq = tid & 15;
  const int dg = tid >> 4;
  const float qscale = 0.18033688011112042f;  // 1/sqrt(64) * log2(e)

  const int q0 = qblk * 64 + halfsel * 32 + wv * 16;

  const u16* qrow = qkv + base + (long)(q0 + l15) * 1536 + h * 64;
  bf16x8 qf0 = scale8(*(const u16x8*)(qrow + g * 8), qscale);
  bf16x8 qf1 = scale8(*(const u16x8*)(qrow + 32 + g * 8), qscale);

  f32x4 o[4] = {};
  float mrun[4] = {-1e30f, -1e30f, -1e30f, -1e30f};
  float lrun[4] = {0.f, 0.f, 0.f, 0.f};
  const int kvend = qblk * 64 + 64;

  u16x8 vreg[4];
#pragma unroll
  for (int i = 0; i < 4; i++) {
    int chunk = i * 128 + tid;
    int row = chunk >> 3, c8 = chunk & 7;
    async16(kbase + (long)row * 1536 + (c8 ^ (row & 7)) * 8,
            &Ks[0][(i * 128 + wv * 64) * 8]);
  }
#pragma unroll
  for (int t = 0; t < 4; t++)
    vreg[t] = *(const u16x8*)(vbase + (long)(kq + 16 * t) * 1536 + dg * 8);
#pragma unroll
  for (int e = 0; e < 8; e++) {
    int d = dg * 8 + e;
    u32x2 wq = { (unsigned)vreg[0][e] | ((unsigned)vreg[1][e] << 16),
                 (unsigned)vreg[2][e] | ((unsigned)vreg[3][e] << 16) };
    *(u32x2*)(&Vt[0][d * 72 + kq * 4]) = wq;
  }
  __syncthreads();

  int cur = 0;
  for (int j0 = 0; j0 < kvend; j0 += 64, cur ^= 1) {
    const bool more = (j0 + 64) < kvend;
    if (more) {
      int jn = j0 + 64;
#pragma unroll
      for (int i = 0; i < 4; i++) {
        int chunk = i * 128 + tid;
        int row = chunk >> 3, c8 = chunk & 7;
        async16(kbase + (long)(jn + row) * 1536 + (c8 ^ (row & 7)) * 8,
                &Ks[cur ^ 1][(i * 128 + wv * 64) * 8]);
      }
#pragma unroll
      for (int t = 0; t < 4; t++)
        vreg[t] = *(const u16x8*)(vbase + (long)(jn + kq + 16 * t) * 1536 + dg * 8);
    }

    f32x4 s[4] = {};
    const u16* kp = Ks[cur];
#pragma unroll
    for (int t = 0; t < 4; t++) {
      int row = t * 16 + l15;
      const u16* kr = kp + row * 64;
      bf16x8 k0 = *(const bf16x8*)(kr + ((g ^ (row & 7)) * 8));
      bf16x8 k1 = *(const bf16x8*)(kr + (((4 + g) ^ (row & 7)) * 8));
      s[t] = __builtin_amdgcn_mfma_f32_16x16x32_bf16(qf0, k0, s[t], 0, 0, 0);
      s[t] = __builtin_amdgcn_mfma_f32_16x16x32_bf16(qf1, k1, s[t], 0, 0, 0);
    }

    const bool diag = (j0 + 64) == kvend;
    u16* pw = Ps[wv];
#pragma unroll
    for (int r = 0; r < 4; r++) {
      int row = q0 + g * 4 + r;
      float v0 = s[0][r], v1 = s[1][r], v2 = s[2][r], v3 = s[3][r];
      if (diag) {
        if (j0 +      l15 > row) v0 = -1e30f;
        if (j0 + 16 + l15 > row) v1 = -1e30f;
        if (j0 + 32 + l15 > row) v2 = -1e30f;
        if (j0 + 48 + l15 > row) v3 = -1e30f;
      }
      float mloc = fmaxf(fmaxf(v0, v1), fmaxf(v2, v3));
      float m = mrun[r];
      if (!__all(mloc <= m + 8.0f)) {
        float mx = mloc;
        mx = fmaxf(mx, __shfl_xor(mx, 1));
        mx = fmaxf(mx, __shfl_xor(mx, 2));
        mx = fmaxf(mx, __shfl_xor(mx, 4));
        mx = fmaxf(mx, __shfl_xor(mx, 8));
        float mn = fmaxf(m, mx);
        float sc2 = exp2f(m - mn);
        lrun[r] *= sc2;
#pragma unroll
        for (int dt = 0; dt < 4; dt++) o[dt][r] *= sc2;
        m = mn; mrun[r] = mn;
      }
      float e0 = exp2f(v0 - m), e1 = exp2f(v1 - m);
      float e2 = exp2f(v2 - m), e3 = exp2f(v3 - m);
      lrun[r] += (e0 + e1) + (e2 + e3);
      u32x2 pkq = { pk_bf16(e0, e1), pk_bf16(e2, e3) };
      int prow = g * 4 + r;
      int byt = prow * 128 + ((((l15 >> 1) ^ (prow & 7)) << 4)) + (l15 & 1) * 8;
      *(u32x2*)((char*)pw + byt) = pkq;
    }

    const u16* vt = Vt[cur];
    bf16x8 pf0 = *(const bf16x8*)((char*)pw + l15 * 128 + (((g) ^ (l15 & 7)) << 4));
    bf16x8 pf1 = *(const bf16x8*)((char*)pw + l15 * 128 + (((4 + g) ^ (l15 & 7)) << 4));
#pragma unroll
    for (int dt = 0; dt < 4; dt++) {
      int d = dt * 16 + l15;
      bf16x8 vf0 = *(const bf16x8*)(vt + d * 72 + g * 8);
      bf16x8 vf1 = *(const bf16x8*)(vt + d * 72 + 32 + g * 8);
      o[dt] = __builtin_amdgcn_mfma_f32_16x16x32_bf16(pf0, vf0, o[dt], 0, 0, 0);
      o[dt] = __builtin_amdgcn_mfma_f32_16x16x32_bf16(pf1, vf1, o[dt], 0, 0, 0);
    }

    if (more) {
#pragma unroll
      for (int e = 0; e < 8; e++) {
        int d = dg * 8 + e;
        u32x2 wq = { (unsigned)vreg[0][e] | ((unsigned)vreg[1][e] << 16),
                     (unsigned)vreg[2][e] | ((unsigned)vreg[3][e] << 16) };
        *(u32x2*)(&Vt[cur ^ 1][d * 72 + kq * 4]) = wq;
      }
    }
    __syncthreads();
  }

#pragma unroll
  for (int r = 0; r < 4; r++) {
    float ls = lrun[r];
    ls += __shfl_xor(ls, 1); ls += __shfl_xor(ls, 2);
    ls += __shfl_xor(ls, 4); ls += __shfl_xor(ls, 8);
    float inv = 1.0f / ls;
    int row = q0 + g * 4 + r;
    u16* orow = out + (long)(b * T_ + row) * C_ + h * 64;
#pragma unroll
    for (int dt = 0; dt < 4; dt++)
      orow[dt * 16 + l15] = f2b(o[dt][r] * inv);
  }
}

// ---------------- host launcher ----------------
extern "C" void kernel_launch(void* const* d_in, const int* in_sizes, int n_in,
                              void* d_out, int out_size, void* d_ws, size_t ws_size,
                              hipStream_t stream) {
  const int*   idx    = (const int*)  d_in[0];
  const float* wte    = (const float*)d_in[1];
  const float* wpe    = (const float*)d_in[2];
  const float* ln1w   = (const float*)d_in[3];
  const float* ln1b   = (const float*)d_in[4];
  const float* wattn  = (const float*)d_in[5];
  const float* wcproj = (const float*)d_in[6];
  const float* ln2w   = (const float*)d_in[7];
  const float* ln2b   = (const float*)d_in[8];
  const float* wfc    = (const float*)d_in[9];
  const float* wproj2 = (const float*)d_in[10];
  const float* lnfw   = (const float*)d_in[11];
  const float* lnfb   = (const float*)d_in[12];
  float* out = (float*)d_out;

  char* p = (char*)d_ws;
  size_t off = 0;
  auto alloc = [&](size_t bytes) -> void* {
    void* r = p + off; off += (bytes + 255) & ~(size_t)255; return r;
  };
  float* x    = (float*)alloc((size_t)M_ * C_ * 4);
  u16* xn     = (u16*)alloc((size_t)M_ * C_ * 2);
  u16* qkvb   = (u16*)alloc((size_t)M_ * 3 * C_ * 2);
  u16* attb   = (u16*)alloc((size_t)M_ * C_ * 2);
  u16* hb     = (u16*)alloc((size_t)M_ * FF_ * 2);
  u16* wteB   = (u16*)alloc((size_t)V_ * C_ * 2);
  u16* wattnB = (u16*)alloc((size_t)L_ * 3 * C_ * C_ * 2);
  u16* wprojB = (u16*)alloc((size_t)L_ * C_ * C_ * 2);
  u16* wfcB   = (u16*)alloc((size_t)L_ * FF_ * C_ * 2);
  u16* wp2B   = (u16*)alloc((size_t)L_ * C_ * FF_ * 2);
  if (off > ws_size) return;

  auto cvt = [&](const float* s, u16* d, long n) {
    int n4 = (int)(n >> 2);
    int blocks = (n4 + 255) / 256; if (blocks > 4096) blocks = 4096;
    cvt_bf16_k<<<dim3(blocks), dim3(256), 0, stream>>>((const f32x4*)s, (u16x4*)d, n4);
  };
  cvt(wte, wteB, (long)V_ * C_);
  cvt(wattn, wattnB, (long)L_ * 3 * C_ * C_);
  cvt(wcproj, wprojB, (long)L_ * C_ * C_);
  cvt(wfc, wfcB, (long)L_ * FF_ * C_);
  cvt(wproj2, wp2B, (long)L_ * C_ * FF_);

  embed_k<<<dim3(M_ * C_ / 4 / 256), dim3(256), 0, stream>>>(idx, wte, wpe, x);

  for (int l = 0; l < L_; l++) {
    ln_k<<<dim3(M_ / 4), dim3(256), 0, stream>>>(x, ln1w + l * C_, ln1b + l * C_, xn);
    gemm_bt_k<0, 64><<<dim3(12, 64), dim3(256), 0, stream>>>(
        xn, wattnB + (size_t)l * 3 * C_ * C_, qkvb, nullptr, 3 * C_, C_, 3 * C_);
    attn_k<<<dim3(64, B_ * H_), dim3(128), 0, stream>>>(qkvb, attb);
    gemm_bt_k<1, 64><<<dim3(4, 64), dim3(256), 0, stream>>>(
        attb, wprojB + (size_t)l * C_ * C_, nullptr, x, C_, C_, C_);
    ln_k<<<dim3(M_ / 4), dim3(256), 0, stream>>>(x, ln2w + l * C_, ln2b + l * C_, xn);
    gemm_bt_k<2, 128><<<dim3(16, 32), dim3(256), 0, stream>>>(
        xn, wfcB + (size_t)l * FF_ * C_, hb, nullptr, FF_, C_, FF_);
    gemm_bt_k<1, 64><<<dim3(4, 64), dim3(256), 0, stream>>>(
        hb, wp2B + (size_t)l * C_ * FF_, nullptr, x, C_, FF_, C_);
  }
  ln_k<<<dim3(M_ / 4), dim3(256), 0, stream>>>(x, lnfw, lnfb, xn);
  gemm_lmhead_k<<<dim3(((V_ + 127) / 128) * (M_ / 256)), dim3(512), 0, stream>>>(
      xn, wteB, out, V_);
}